// Round 10
// baseline (130.765 us; speedup 1.0000x reference)
//
#include <hip/hip_runtime.h>
#include <hip/hip_bf16.h>

// Problem constants (fixed by the reference):
constexpr int NB = 256;   // batch
constexpr int SQ = 512;   // sequence length
constexpr int ED = 512;   // encoder dim
constexpr int DD = 512;   // decoder dim
constexpr int UU = 64;    // attention units
constexpr int NT = 32;    // s-tiles per batch (wave-sized tiles)
constexpr int TS = 16;    // rows per tile = one wave's MFMA M

typedef __attribute__((ext_vector_type(8))) short bf16x8;
typedef __attribute__((ext_vector_type(4))) float f32x4;
typedef __attribute__((ext_vector_type(4))) unsigned int u32x4;

__device__ __forceinline__ unsigned short bf16_rne(float f) {
  unsigned int u = __float_as_uint(f);
  u += 0x7FFFu + ((u >> 16) & 1u);
  return (unsigned short)(u >> 16);
}

// Truncate-truncate pair split: v ~= hi + lo to ~2^-16 rel.
__device__ __forceinline__ uint2 split2(float v0, float v1) {
  unsigned int u0 = __float_as_uint(v0), u1 = __float_as_uint(v1);
  unsigned int h0 = u0 & 0xFFFF0000u, h1 = u1 & 0xFFFF0000u;
  unsigned int hi = (u0 >> 16) | h1;
  float r0 = v0 - __uint_as_float(h0);
  float r1 = v1 - __uint_as_float(h1);
  unsigned int lo = (__float_as_uint(r0) >> 16) | (__float_as_uint(r1) & 0xFFFF0000u);
  return make_uint2(hi, lo);
}

// ws layout (bytes):
//   [0,       65536)   : w2 bf16-hi MFMA B-fragments (hi only)
//   [131072,  196608)  : dec[256][64]
//   [196608,  229376)  : mbuf[256][32]
//   [229376,  262144)  : lbuf[256][32]
//   [262144, 17039360) : ctile[256][32][512]
constexpr size_t WS_DEC   = 131072;
constexpr size_t WS_MBUF  = 196608;
constexpr size_t WS_LBUF  = 229376;
constexpr size_t WS_CTILE = 262144;

// ---------------------------------------------------------------------------
// Kernel P: fused prep. Blocks 0..127: w2 -> bf16-hi B-fragments
// (layout: ks*2048 + nt*512 + lane*8 + j). Blocks 128..383: dec_proj.
// ---------------------------------------------------------------------------
__global__ __launch_bounds__(256) void prep_all(
    const float* __restrict__ w2, unsigned short* __restrict__ wsb,
    const float* __restrict__ dh, const float* __restrict__ w1,
    const float* __restrict__ w1b, const float* __restrict__ w2b,
    float* __restrict__ dec_ws) {
  const int blk = blockIdx.x;
  __shared__ float red[256];
  if (blk < 128) {
    int tid = blk * 256 + threadIdx.x;   // 0..32767
    int j    = tid & 7;
    int lane = (tid >> 3) & 63;
    int nt   = (tid >> 9) & 3;
    int ks   = tid >> 11;
    int e = ks * 32 + (lane >> 4) * 8 + j;
    int u = nt * 16 + (lane & 15);
    wsb[tid] = bf16_rne(w2[e * UU + u]);
  } else {
    const int b = blk - 128;
    const int t = threadIdx.x;
    const int wave = t >> 6;
    const int lane = t & 63;
    const float* dhb = dh + (size_t)b * DD;
    const int e0 = wave * 128;
    float s = 0.f;
    #pragma unroll 8
    for (int i = 0; i < 128; ++i) {
      int e = e0 + i;
      s = fmaf(dhb[e], w1[e * UU + lane], s);
    }
    red[t] = s;
    __syncthreads();
    if (t < 64) {
      float d = w1b[t] + w2b[t] + red[t] + red[64 + t] + red[128 + t] + red[192 + t];
      dec_ws[b * UU + t] = d;
    }
  }
}

// ---------------------------------------------------------------------------
// Kernel A: ONE WAVE PER BLOCK, one 16-row tile each. 8192 blocks.
// Zero __syncthreads, zero LDS: every wave fully independent and self-paced.
// Rounds 1-9 post-mortem: all pipes idle (Mfma 6%, VALU 12-17%, HBM 20%),
// L3-warm == HBM-cold -> stall-bound from lock-step multi-wave phase
// structure. This removes ALL intra-block coupling.
// B-hi fragments stream from L2 (same 64 KB for all waves, broadcast-hot);
// A: 3-deep register prefetch; softmax over the wave's 16 rows in shuffles;
// flash combine over 32 tiles/batch in kernel B.
// ---------------------------------------------------------------------------
__global__ __launch_bounds__(64, 4) void attn_wave(
    const float* __restrict__ x,
    const float* __restrict__ vk,
    const unsigned short* __restrict__ wsb,
    const float* __restrict__ dec_ws,
    float* __restrict__ mbuf, float* __restrict__ lbuf,
    float* __restrict__ ctile,
    float* __restrict__ out)
{
  const int bid = blockIdx.x;
  const int b  = bid >> 5;
  const int tl = bid & 31;
  const int lane = threadIdx.x;        // 0..63
  const int ul = lane & 15;            // MFMA col-in-tile / A row select
  const int g  = lane >> 4;            // row group
  const int row0 = tl * TS;

  // ---- projection GEMM for 16 rows (A: global->reg, B: L2 broadcast) -----
  const float* aptr = x + ((size_t)(b * SQ + row0 + ul)) * ED + g * 8;
  const unsigned short* bptr = wsb + lane * 8;

  const f32x4 zero4 = {0.f, 0.f, 0.f, 0.f};
  f32x4 acc[4];
  #pragma unroll
  for (int n = 0; n < 4; ++n) acc[n] = zero4;

  float4 pa0[3], pa1[3];
  #pragma unroll
  for (int q = 0; q < 3; ++q) {
    pa0[q] = *(const float4*)(aptr + q * 32);
    pa1[q] = *(const float4*)(aptr + q * 32 + 4);
  }

  #pragma unroll
  for (int k = 0; k < 16; ++k) {
    float4 a0 = pa0[k % 3], a1 = pa1[k % 3];
    if (k < 13) {
      pa0[k % 3] = *(const float4*)(aptr + (k + 3) * 32);
      pa1[k % 3] = *(const float4*)(aptr + (k + 3) * 32 + 4);
    }
    bf16x8 bhi[4];
    #pragma unroll
    for (int n = 0; n < 4; ++n) {
      bhi[n] = *(const bf16x8*)(bptr + k * 2048 + n * 512);
    }
    uint2 p0 = split2(a0.x, a0.y);
    uint2 p1 = split2(a0.z, a0.w);
    uint2 p2 = split2(a1.x, a1.y);
    uint2 p3 = split2(a1.z, a1.w);
    u32x4 hi, lo;
    hi[0] = p0.x; lo[0] = p0.y;
    hi[1] = p1.x; lo[1] = p1.y;
    hi[2] = p2.x; lo[2] = p2.y;
    hi[3] = p3.x; lo[3] = p3.y;
    bf16x8 ahi = __builtin_bit_cast(bf16x8, hi);
    bf16x8 alo = __builtin_bit_cast(bf16x8, lo);
    #pragma unroll
    for (int n = 0; n < 4; ++n) {
      acc[n] = __builtin_amdgcn_mfma_f32_16x16x32_bf16(ahi, bhi[n], acc[n], 0, 0, 0);
      acc[n] = __builtin_amdgcn_mfma_f32_16x16x32_bf16(alo, bhi[n], acc[n], 0, 0, 0);
    }
  }

  // ---- scores + 16-row softmax, all in shuffles ---------------------------
  // C/D layout (m89/m91): row = g*4 + r, col u = n*16 + ul
  float psc[4];
  {
    const float* decb = dec_ws + b * UU;
    float dv[4], vv[4];
    #pragma unroll
    for (int n = 0; n < 4; ++n) { dv[n] = decb[n * 16 + ul]; vv[n] = vk[n * 16 + ul]; }
    #pragma unroll
    for (int r = 0; r < 4; ++r) {
      float s = 0.f;
      #pragma unroll
      for (int n = 0; n < 4; ++n) {
        float z = acc[n][r] + dv[n];
        float ez = __expf(2.f * z);              // tanh via exp
        float th = 1.f - 2.f / (ez + 1.f);
        s = fmaf(th, vv[n], s);
      }
      s += __shfl_xor(s, 1);
      s += __shfl_xor(s, 2);
      s += __shfl_xor(s, 4);
      s += __shfl_xor(s, 8);     // now all 16 lanes of the col group hold it
      psc[r] = s;
    }
  }
  float m = fmaxf(fmaxf(psc[0], psc[1]), fmaxf(psc[2], psc[3]));
  m = fmaxf(m, __shfl_xor(m, 16));
  m = fmaxf(m, __shfl_xor(m, 32));   // tile max, all lanes
  float p[4];
  float lsum = 0.f;
  #pragma unroll
  for (int r = 0; r < 4; ++r) { p[r] = __expf(psc[r] - m); lsum += p[r]; }
  lsum += __shfl_xor(lsum, 16);
  lsum += __shfl_xor(lsum, 32);      // tile exp-sum, all lanes

  if (ul == 0) {
    float* att = out + (size_t)NB * ED + (size_t)b * SQ + row0;
    #pragma unroll
    for (int r = 0; r < 4; ++r) att[g * 4 + r] = p[r];   // unnormalized
  }
  if (lane == 0) {
    mbuf[b * NT + tl] = m;
    lbuf[b * NT + tl] = lsum;
  }

  // ---- partial context for this tile: c[e] = sum_{16 rows} p x[row,e] -----
  // lane owns cols [lane*8, lane*8+8); rows' p broadcast via shuffle.
  {
    const float* xrow = x + ((size_t)(b * SQ + row0)) * ED + lane * 8;
    f32x4 c0 = zero4, c1 = zero4;
    #pragma unroll
    for (int i = 0; i < 16; ++i) {
      float pi = __shfl(p[i & 3], (i >> 2) << 4);
      const float* xr = xrow + (size_t)i * ED;
      float4 v0 = *(const float4*)xr;
      float4 v1 = *(const float4*)(xr + 4);
      c0[0] = fmaf(pi, v0.x, c0[0]);
      c0[1] = fmaf(pi, v0.y, c0[1]);
      c0[2] = fmaf(pi, v0.z, c0[2]);
      c0[3] = fmaf(pi, v0.w, c0[3]);
      c1[0] = fmaf(pi, v1.x, c1[0]);
      c1[1] = fmaf(pi, v1.y, c1[1]);
      c1[2] = fmaf(pi, v1.z, c1[2]);
      c1[3] = fmaf(pi, v1.w, c1[3]);
    }
    float* ct = ctile + ((size_t)b * NT + tl) * ED + lane * 8;
    *(f32x4*)ct = c0;
    *(f32x4*)(ct + 4) = c1;
  }
}

// ---------------------------------------------------------------------------
// Kernel B: combine 32 tiles per batch (flash algebra).
// att *= e^{m_t-M}/L in place; ctx = sum_t ctile_t e^{m_t-M}/L.
// ---------------------------------------------------------------------------
__global__ __launch_bounds__(256) void combine(
    const float* __restrict__ mbuf, const float* __restrict__ lbuf,
    const float* __restrict__ ctile, float* __restrict__ out) {
  const int b = blockIdx.x;
  const int t = threadIdx.x;
  __shared__ float sc_s[NT];

  float M = -1e30f;
  #pragma unroll 8
  for (int j = 0; j < NT; ++j) M = fmaxf(M, mbuf[b * NT + j]);
  float L = 0.f;
  #pragma unroll 8
  for (int j = 0; j < NT; ++j) L += lbuf[b * NT + j] * __expf(mbuf[b * NT + j] - M);
  const float inv = 1.f / L;
  if (t < NT) sc_s[t] = __expf(mbuf[b * NT + t] - M) * inv;
  __syncthreads();

  float* att = out + (size_t)NB * ED + (size_t)b * SQ;
  #pragma unroll
  for (int s = t; s < SQ; s += 256) att[s] *= sc_s[s >> 4];

  const float* ct = ctile + (size_t)b * NT * ED;
  #pragma unroll
  for (int e = t; e < ED; e += 256) {
    float c = 0.f;
    #pragma unroll 8
    for (int j = 0; j < NT; ++j) c = fmaf(ct[j * ED + e], sc_s[j], c);
    out[(size_t)b * ED + e] = c;
  }
}

// ---------------------------------------------------------------------------
extern "C" void kernel_launch(void* const* d_in, const int* in_sizes, int n_in,
                              void* d_out, int out_size, void* d_ws, size_t ws_size,
                              hipStream_t stream) {
  const float* dh  = (const float*)d_in[0];
  const float* x   = (const float*)d_in[1];
  const float* w1  = (const float*)d_in[2];
  const float* w1b = (const float*)d_in[3];
  const float* w2  = (const float*)d_in[4];
  const float* w2b = (const float*)d_in[5];
  const float* vk  = (const float*)d_in[6];
  // d_in[7] = v_bias: softmax exactly invariant -> unused.
  unsigned short* wsb = (unsigned short*)d_ws;
  float* dec_ws = (float*)((char*)d_ws + WS_DEC);
  float* mbuf   = (float*)((char*)d_ws + WS_MBUF);
  float* lbuf   = (float*)((char*)d_ws + WS_LBUF);
  float* ctile  = (float*)((char*)d_ws + WS_CTILE);
  float* out = (float*)d_out;

  prep_all<<<384, 256, 0, stream>>>(w2, wsb, dh, w1, w1b, w2b, dec_ws);
  attn_wave<<<NB * NT, 64, 0, stream>>>(x, vk, wsb, dec_ws, mbuf, lbuf, ctile, out);
  combine<<<NB, 256, 0, stream>>>(mbuf, lbuf, ctile, out);
}

// Round 12
// 101.724 us; speedup vs baseline: 1.2855x; 1.2855x over previous
//
#include <hip/hip_runtime.h>
#include <hip/hip_bf16.h>

// Problem constants (fixed by the reference):
constexpr int NB = 256;   // batch
constexpr int SQ = 512;   // sequence length
constexpr int ED = 512;   // encoder dim
constexpr int DD = 512;   // decoder dim
constexpr int UU = 64;    // attention units
constexpr int NT = 32;    // 16-row tiles per batch
constexpr int TS = 16;    // rows per tile (one wave's MFMA M)

typedef __attribute__((ext_vector_type(8))) short bf16x8;
typedef __attribute__((ext_vector_type(4))) float f32x4;

#define WAITVM(n) asm volatile("s_waitcnt vmcnt(" #n ")" ::: "memory")

__device__ __forceinline__ void stage16(const void* g, void* l) {
  __builtin_amdgcn_global_load_lds(
      (const __attribute__((address_space(1))) void*)g,
      (__attribute__((address_space(3))) void*)l, 16, 0, 0);
}

__device__ __forceinline__ unsigned short bf16_rne(float f) {
  unsigned int u = __float_as_uint(f);
  u += 0x7FFFu + ((u >> 16) & 1u);
  return (unsigned short)(u >> 16);
}

// Truncate-truncate pair split: v ~= hi + lo to ~2^-16 rel.
__device__ __forceinline__ uint2 split2(float v0, float v1) {
  unsigned int u0 = __float_as_uint(v0), u1 = __float_as_uint(v1);
  unsigned int h0 = u0 & 0xFFFF0000u, h1 = u1 & 0xFFFF0000u;
  unsigned int hi = (u0 >> 16) | h1;
  float r0 = v0 - __uint_as_float(h0);
  float r1 = v1 - __uint_as_float(h1);
  unsigned int lo = (__float_as_uint(r0) >> 16) | (__float_as_uint(r1) & 0xFFFF0000u);
  return make_uint2(hi, lo);
}

// ws layout (bytes):
//   [0,       65536)   : w2 bf16-hi MFMA B-fragments
//   [131072,  196608)  : dec[256][64]
//   [196608,  229376)  : mbuf[256][32]
//   [229376,  262144)  : lbuf[256][32]
//   [262144, 17039360) : ctile[256][32][512]
constexpr size_t WS_DEC   = 131072;
constexpr size_t WS_MBUF  = 196608;
constexpr size_t WS_LBUF  = 229376;
constexpr size_t WS_CTILE = 262144;

// ---------------------------------------------------------------------------
// Kernel P: fused prep. Blocks 0..127: w2 -> bf16-hi B-fragments
// (layout: ks*2048 + nt*512 + lane*8 + j). Blocks 128..383: dec_proj.
// ---------------------------------------------------------------------------
__global__ __launch_bounds__(256) void prep_all(
    const float* __restrict__ w2, unsigned short* __restrict__ wsb,
    const float* __restrict__ dh, const float* __restrict__ w1,
    const float* __restrict__ w1b, const float* __restrict__ w2b,
    float* __restrict__ dec_ws) {
  const int blk = blockIdx.x;
  __shared__ float red[256];
  if (blk < 128) {
    int tid = blk * 256 + threadIdx.x;   // 0..32767
    int j    = tid & 7;
    int lane = (tid >> 3) & 63;
    int nt   = (tid >> 9) & 3;
    int ks   = tid >> 11;
    int e = ks * 32 + (lane >> 4) * 8 + j;
    int u = nt * 16 + (lane & 15);
    wsb[tid] = bf16_rne(w2[e * UU + u]);
  } else {
    const int b = blk - 128;
    const int t = threadIdx.x;
    const int wave = t >> 6;
    const float* dhb = dh + (size_t)b * DD;
    const int e0 = wave * 128;
    float s = 0.f;
    #pragma unroll 8
    for (int i = 0; i < 128; ++i) {
      int e = e0 + i;
      s = fmaf(dhb[e], w1[e * UU + (t & 63)], s);
    }
    red[t] = s;
    __syncthreads();
    if (t < 64) {
      float d = w1b[t] + w2b[t] + red[t] + red[64 + t] + red[128 + t] + red[192 + t];
      dec_ws[b * UU + t] = d;
    }
  }
}

// ---------------------------------------------------------------------------
// Kernel A: 1024 blocks (b x 4), 512 threads = 8 waves; wave = one 16-row
// tile. DEPTH + INDEPENDENCE:
//  - A staged via global_load_lds into a WAVE-PRIVATE 4-slot ring with
//    depth-3 prefetch (round-11 bug: depth-4 on 4 slots staged chunk k+4
//    into slot k&3 WHILE reading chunk k -> race, absmax 0.24. Depth 3
//    writes slot (k+3)&3 != k&3; that slot's reads issued at iter k-1,
//    strictly earlier in program order -> no race).
//  - counted per-wave vmcnt(4/2/0), ~6 KB in flight per wave, 48 KB/CU,
//    ZERO barriers in the k-loop: every wave self-paced.
//  - B-hi frags in 64 KB shared LDS (DMA'd in prologue), read via ds_read
//    (lgkmcnt) so the vmcnt budget stays A-only.
//  - epilogue entirely wave-local (16-row shuffle softmax + context).
//  - A ds_reads conflict-free via both-sides XOR swizzle (^((row&7)<<4)).
// ---------------------------------------------------------------------------
__global__ __launch_bounds__(512, 2) void attn_blk(
    const float* __restrict__ x,
    const float* __restrict__ vk,
    const unsigned short* __restrict__ wsb,
    const float* __restrict__ dec_ws,
    float* __restrict__ mbuf, float* __restrict__ lbuf,
    float* __restrict__ ctile,
    float* __restrict__ out)
{
  const int b  = blockIdx.x >> 2;
  const int q4 = blockIdx.x & 3;
  const int t = threadIdx.x;
  const int wave = t >> 6;
  const int lane = t & 63;

  __shared__ __align__(16) unsigned short blds[32768];      // 64 KB B-hi
  __shared__ __align__(16) unsigned char ring[8][4][2048];  // 64 KB A ring
  __shared__ float dec_lds[64];
  __shared__ float v_lds[64];

  // ---- prologue: DMA B->LDS (wave w stages its 8 KB slice), dec/v loads ---
  {
    const char* wb = (const char*)wsb;
    char* bb = (char*)blds;
    #pragma unroll
    for (int i = 0; i < 8; ++i) {
      int off = wave * 8192 + i * 1024 + lane * 16;
      stage16(wb + off, bb + off);
    }
  }
  if (t < 64) {
    dec_lds[t] = dec_ws[b * UU + t];
    v_lds[t] = vk[t];
  }
  WAITVM(0);           // own wave's B DMAs done
  __syncthreads();     // all waves' slices + dec/v visible; ONLY barrier

  // ---- projection GEMM: per-wave self-paced DMA ring ----------------------
  const int row0 = q4 * 128 + wave * 16;
  const int ul = lane & 15;            // row within tile (for A), col sel
  const int g  = lane >> 4;            // k-group
  const int sw = (lane & 7) << 4;      // == (row&7)<<4 for A reads
  const char* gsrc = (const char*)x + (size_t)(b * SQ + row0) * 2048;

  // stage chunk k into slot: chunk = 16 rows x 128 B, source pre-swizzled
  auto stageA = [&](int k, int slot) {
    #pragma unroll
    for (int s2 = 0; s2 < 2; ++s2) {
      int L = s2 * 1024 + lane * 16;
      int row = L >> 7, o = L & 127;
      stage16(gsrc + (size_t)row * 2048 + (size_t)(k * 128 + (o ^ ((row & 7) << 4))),
              &ring[wave][slot][L]);
    }
  };

  const f32x4 zero4 = {0.f, 0.f, 0.f, 0.f};
  f32x4 acc[4];
  #pragma unroll
  for (int n = 0; n < 4; ++n) acc[n] = zero4;

  stageA(0, 0); stageA(1, 1); stageA(2, 2);   // 6 ops in flight (depth 3)

  #pragma unroll
  for (int k = 0; k < 16; ++k) {
    // chunk k landed when newer chunks' ops remain: k<=13 -> 4; 14 -> 2; 15 -> 0
    if (k <= 13)      { WAITVM(4); }
    else if (k == 14) { WAITVM(2); }
    else              { WAITVM(0); }
    if (k < 13) stageA(k + 3, (k + 3) & 3);   // distinct slot from k&3

    const unsigned char* Ab = &ring[wave][k & 3][0] + ul * 128;
    f32x4 a0 = *(const f32x4*)(Ab + ((g * 32) ^ sw));
    f32x4 a1 = *(const f32x4*)(Ab + ((g * 32 + 16) ^ sw));
    bf16x8 bhi[4];
    #pragma unroll
    for (int n = 0; n < 4; ++n) {
      bhi[n] = *(const bf16x8*)&blds[k * 2048 + n * 512 + lane * 8];
    }
    uint2 p0 = split2(a0[0], a0[1]);
    uint2 p1 = split2(a0[2], a0[3]);
    uint2 p2 = split2(a1[0], a1[1]);
    uint2 p3 = split2(a1[2], a1[3]);
    unsigned int hiw[4] = {p0.x, p1.x, p2.x, p3.x};
    unsigned int low[4] = {p0.y, p1.y, p2.y, p3.y};
    bf16x8 ahi, alo;
    memcpy(&ahi, hiw, 16);
    memcpy(&alo, low, 16);
    #pragma unroll
    for (int n = 0; n < 4; ++n) {
      acc[n] = __builtin_amdgcn_mfma_f32_16x16x32_bf16(ahi, bhi[n], acc[n], 0, 0, 0);
      acc[n] = __builtin_amdgcn_mfma_f32_16x16x32_bf16(alo, bhi[n], acc[n], 0, 0, 0);
    }
  }

  // ---- wave-local scores + 16-row softmax (shuffles only, no barriers) ----
  // C/D layout (m89/m91): row = g*4 + r, col u = n*16 + ul
  float psc[4];
  {
    float dv[4], vv[4];
    #pragma unroll
    for (int n = 0; n < 4; ++n) { dv[n] = dec_lds[n * 16 + ul]; vv[n] = v_lds[n * 16 + ul]; }
    #pragma unroll
    for (int r = 0; r < 4; ++r) {
      float s = 0.f;
      #pragma unroll
      for (int n = 0; n < 4; ++n) {
        float z = acc[n][r] + dv[n];
        float ez = __expf(2.f * z);              // tanh via exp
        float th = 1.f - 2.f / (ez + 1.f);
        s = fmaf(th, vv[n], s);
      }
      s += __shfl_xor(s, 1);
      s += __shfl_xor(s, 2);
      s += __shfl_xor(s, 4);
      s += __shfl_xor(s, 8);     // all 16 lanes of the row group hold it
      psc[r] = s;
    }
  }
  float m = fmaxf(fmaxf(psc[0], psc[1]), fmaxf(psc[2], psc[3]));
  m = fmaxf(m, __shfl_xor(m, 16));
  m = fmaxf(m, __shfl_xor(m, 32));   // tile max, all lanes
  float p[4];
  float lsum = 0.f;
  #pragma unroll
  for (int r = 0; r < 4; ++r) { p[r] = __expf(psc[r] - m); lsum += p[r]; }
  lsum += __shfl_xor(lsum, 16);
  lsum += __shfl_xor(lsum, 32);      // tile exp-sum, all lanes

  const int tl = q4 * 8 + wave;      // global tile id 0..31
  if (ul == 0) {
    float* att = out + (size_t)NB * ED + (size_t)b * SQ + row0;
    #pragma unroll
    for (int r = 0; r < 4; ++r) att[g * 4 + r] = p[r];   // unnormalized
  }
  if (lane == 0) {
    mbuf[b * NT + tl] = m;
    lbuf[b * NT + tl] = lsum;
  }

  // ---- partial context (L2-hot rows, 4-row rotating prefetch) -------------
  {
    const float* xrow = x + (size_t)(b * SQ + row0) * ED + lane * 8;
    float4 pr0[4], pr1[4];
    #pragma unroll
    for (int q = 0; q < 4; ++q) {
      pr0[q] = *(const float4*)(xrow + (size_t)q * ED);
      pr1[q] = *(const float4*)(xrow + (size_t)q * ED + 4);
    }
    f32x4 c0 = zero4, c1 = zero4;
    #pragma unroll
    for (int i = 0; i < 16; ++i) {
      float4 v0 = pr0[i & 3], v1 = pr1[i & 3];
      if (i < 12) {
        pr0[i & 3] = *(const float4*)(xrow + (size_t)(i + 4) * ED);
        pr1[i & 3] = *(const float4*)(xrow + (size_t)(i + 4) * ED + 4);
      }
      float pi = __shfl(p[i & 3], (i >> 2) << 4);
      c0[0] = fmaf(pi, v0.x, c0[0]);
      c0[1] = fmaf(pi, v0.y, c0[1]);
      c0[2] = fmaf(pi, v0.z, c0[2]);
      c0[3] = fmaf(pi, v0.w, c0[3]);
      c1[0] = fmaf(pi, v1.x, c1[0]);
      c1[1] = fmaf(pi, v1.y, c1[1]);
      c1[2] = fmaf(pi, v1.z, c1[2]);
      c1[3] = fmaf(pi, v1.w, c1[3]);
    }
    float* ct = ctile + ((size_t)b * NT + tl) * ED + lane * 8;
    *(f32x4*)ct = c0;
    *(f32x4*)(ct + 4) = c1;
  }
}

// ---------------------------------------------------------------------------
// Kernel B: combine 32 tiles per batch (flash algebra).
// att *= e^{m_t-M}/L in place; ctx = sum_t ctile_t e^{m_t-M}/L.
// ---------------------------------------------------------------------------
__global__ __launch_bounds__(256) void combine(
    const float* __restrict__ mbuf, const float* __restrict__ lbuf,
    const float* __restrict__ ctile, float* __restrict__ out) {
  const int b = blockIdx.x;
  const int t = threadIdx.x;
  __shared__ float sc_s[NT];

  float M = -1e30f;
  #pragma unroll 8
  for (int j = 0; j < NT; ++j) M = fmaxf(M, mbuf[b * NT + j]);
  float L = 0.f;
  #pragma unroll 8
  for (int j = 0; j < NT; ++j) L += lbuf[b * NT + j] * __expf(mbuf[b * NT + j] - M);
  const float inv = 1.f / L;
  if (t < NT) sc_s[t] = __expf(mbuf[b * NT + t] - M) * inv;
  __syncthreads();

  float* att = out + (size_t)NB * ED + (size_t)b * SQ;
  #pragma unroll
  for (int s = t; s < SQ; s += 256) att[s] *= sc_s[s >> 4];

  const float* ct = ctile + (size_t)b * NT * ED;
  #pragma unroll
  for (int e = t; e < ED; e += 256) {
    float c = 0.f;
    #pragma unroll 8
    for (int j = 0; j < NT; ++j) c = fmaf(ct[j * ED + e], sc_s[j], c);
    out[(size_t)b * ED + e] = c;
  }
}

// ---------------------------------------------------------------------------
extern "C" void kernel_launch(void* const* d_in, const int* in_sizes, int n_in,
                              void* d_out, int out_size, void* d_ws, size_t ws_size,
                              hipStream_t stream) {
  const float* dh  = (const float*)d_in[0];
  const float* x   = (const float*)d_in[1];
  const float* w1  = (const float*)d_in[2];
  const float* w1b = (const float*)d_in[3];
  const float* w2  = (const float*)d_in[4];
  const float* w2b = (const float*)d_in[5];
  const float* vk  = (const float*)d_in[6];
  // d_in[7] = v_bias: softmax exactly invariant -> unused.
  unsigned short* wsb = (unsigned short*)d_ws;
  float* dec_ws = (float*)((char*)d_ws + WS_DEC);
  float* mbuf   = (float*)((char*)d_ws + WS_MBUF);
  float* lbuf   = (float*)((char*)d_ws + WS_LBUF);
  float* ctile  = (float*)((char*)d_ws + WS_CTILE);
  float* out = (float*)d_out;

  prep_all<<<384, 256, 0, stream>>>(w2, wsb, dh, w1, w1b, w2b, dec_ws);
  attn_blk<<<NB * 4, 512, 0, stream>>>(x, vk, wsb, dec_ws, mbuf, lbuf, ctile, out);
  combine<<<NB, 256, 0, stream>>>(mbuf, lbuf, ctile, out);
}

// Round 13
// 101.528 us; speedup vs baseline: 1.2880x; 1.0019x over previous
//
#include <hip/hip_runtime.h>
#include <hip/hip_bf16.h>

// Problem constants (fixed by the reference):
constexpr int NB = 256;   // batch
constexpr int SQ = 512;   // sequence length
constexpr int ED = 512;   // encoder dim
constexpr int DD = 512;   // decoder dim
constexpr int UU = 64;    // attention units
constexpr int NT = 32;    // 16-row tiles per batch

typedef __attribute__((ext_vector_type(8))) short bf16x8;
typedef __attribute__((ext_vector_type(4))) float f32x4;

#define WAITVM(n) asm volatile("s_waitcnt vmcnt(" #n ")" ::: "memory")

__device__ __forceinline__ void stage16(const void* g, void* l) {
  __builtin_amdgcn_global_load_lds(
      (const __attribute__((address_space(1))) void*)g,
      (__attribute__((address_space(3))) void*)l, 16, 0, 0);
}

__device__ __forceinline__ unsigned short bf16_rne(float f) {
  unsigned int u = __float_as_uint(f);
  u += 0x7FFFu + ((u >> 16) & 1u);
  return (unsigned short)(u >> 16);
}

// Truncate-truncate pair split: v ~= hi + lo to ~2^-16 rel.
__device__ __forceinline__ uint2 split2(float v0, float v1) {
  unsigned int u0 = __float_as_uint(v0), u1 = __float_as_uint(v1);
  unsigned int h0 = u0 & 0xFFFF0000u, h1 = u1 & 0xFFFF0000u;
  unsigned int hi = (u0 >> 16) | h1;
  float r0 = v0 - __uint_as_float(h0);
  float r1 = v1 - __uint_as_float(h1);
  unsigned int lo = (__float_as_uint(r0) >> 16) | (__float_as_uint(r1) & 0xFFFF0000u);
  return make_uint2(hi, lo);
}

// ws layout (bytes):
constexpr size_t WS_DEC   = 131072;
constexpr size_t WS_MBUF  = 196608;
constexpr size_t WS_LBUF  = 229376;
constexpr size_t WS_CTILE = 262144;

// ---------------------------------------------------------------------------
// Kernel P: fused prep. Blocks 0..127: w2 -> bf16-hi B-fragments
// (layout: ks*2048 + nt*512 + lane*8 + j). Blocks 128..383: dec_proj.
// ---------------------------------------------------------------------------
__global__ __launch_bounds__(256) void prep_all(
    const float* __restrict__ w2, unsigned short* __restrict__ wsb,
    const float* __restrict__ dh, const float* __restrict__ w1,
    const float* __restrict__ w1b, const float* __restrict__ w2b,
    float* __restrict__ dec_ws) {
  const int blk = blockIdx.x;
  __shared__ float red[256];
  if (blk < 128) {
    int tid = blk * 256 + threadIdx.x;   // 0..32767
    int j    = tid & 7;
    int lane = (tid >> 3) & 63;
    int nt   = (tid >> 9) & 3;
    int ks   = tid >> 11;
    int e = ks * 32 + (lane >> 4) * 8 + j;
    int u = nt * 16 + (lane & 15);
    wsb[tid] = bf16_rne(w2[e * UU + u]);
  } else {
    const int b = blk - 128;
    const int t = threadIdx.x;
    const int wave = t >> 6;
    const float* dhb = dh + (size_t)b * DD;
    const int e0 = wave * 128;
    float s = 0.f;
    #pragma unroll 8
    for (int i = 0; i < 128; ++i) {
      int e = e0 + i;
      s = fmaf(dhb[e], w1[e * UU + (t & 63)], s);
    }
    red[t] = s;
    __syncthreads();
    if (t < 64) {
      float d = w1b[t] + w2b[t] + red[t] + red[64 + t] + red[128 + t] + red[192 + t];
      dec_ws[b * UU + t] = d;
    }
  }
}

// ---------------------------------------------------------------------------
// Kernel A: 2048 blocks (b x 8), 256 threads = 4 waves; wave = one 16-row
// tile. COALESCED-CHUNK staging (the round-13 hypothesis): chunk = 16 rows
// x 256 CONTIGUOUS bytes (4 KB) -> every stage16 instruction covers 4 full
// 256-byte runs (vs 8-16 scattered 128B runs in ALL previous rounds, the
// one property that never changed while dur_us sat pinned at ~100 us).
//  - wave-private 3-slot ring, depth 2, no barriers anywhere.
//  - vmcnt ladder is conservative: B-register loads interleave the FIFO
//    (in-order retirement, m135), so waits use upper-bound counts.
//  - B-hi from L2 with 4-slot register prefetch (2 chunks ahead).
//  - LDS 48 KB -> 3 blocks/CU = 12 independent deep streams per CU.
//  - A ds_reads: 4-bit row XOR swizzle -> uniform 8 accesses/bank (b128
//    floor). Wave-local shuffle softmax + context (round-12, verified).
// ---------------------------------------------------------------------------
__global__ __launch_bounds__(256, 3) void attn_blk(
    const float* __restrict__ x,
    const float* __restrict__ vk,
    const unsigned short* __restrict__ wsb,
    const float* __restrict__ dec_ws,
    float* __restrict__ mbuf, float* __restrict__ lbuf,
    float* __restrict__ ctile,
    float* __restrict__ out)
{
  const int b  = blockIdx.x >> 3;
  const int q8 = blockIdx.x & 7;
  const int t = threadIdx.x;
  const int wave = t >> 6;
  const int lane = t & 63;
  const int ul = lane & 15;            // row within tile / col sel
  const int g  = lane >> 4;            // k-subgroup 0..3
  const int swz = ul << 4;             // 4-bit row XOR (bits 4..7)

  __shared__ __align__(16) unsigned char ring[4][3][4096];  // 48 KB

  const int row0w = q8 * 64 + wave * 16;
  const char* gsrcw = (const char*)x + (size_t)(b * SQ + row0w) * 2048;
  const unsigned short* bp = wsb + lane * 8;

  // ---- prologue loads (oldest in vm FIFO; waits below are upper bounds) ---
  float dv[4], vv[4];
  #pragma unroll
  for (int n = 0; n < 4; ++n) {
    dv[n] = dec_ws[b * UU + n * 16 + ul];
    vv[n] = vk[n * 16 + ul];
  }

  // stage chunk c (cols [c*64, c*64+64) fp32) into slot: 4 instrs, each
  // covering 4 rows x 256B contiguous runs; source XOR'd within the run.
  auto stageA = [&](int c, int slot) {
    #pragma unroll
    for (int s2 = 0; s2 < 4; ++s2) {
      int L = s2 * 1024 + lane * 16;
      int row = s2 * 4 + (lane >> 4);
      int o = (lane & 15) * 16;
      stage16(gsrcw + (size_t)row * 2048 + (size_t)(c * 256 + (o ^ ((row & 15) << 4))),
              &ring[wave][slot][L]);
    }
  };

  const f32x4 zero4 = {0.f, 0.f, 0.f, 0.f};
  f32x4 acc[4];
  #pragma unroll
  for (int n = 0; n < 4; ++n) acc[n] = zero4;

  bf16x8 bf[4][4];   // B-hi frags, slot = k&3 (all indices compile-time)

  stageA(0, 0); stageA(1, 1);                 // chunks 0,1 in flight
  #pragma unroll
  for (int n = 0; n < 4; ++n) bf[0][n] = *(const bf16x8*)(bp + 0 * 2048 + n * 512);
  #pragma unroll
  for (int n = 0; n < 4; ++n) bf[1][n] = *(const bf16x8*)(bp + 1 * 2048 + n * 512);

  #pragma unroll
  for (int c = 0; c < 8; ++c) {
    // guarantee chunk c landed: bound = quads issued after stage(c) in FIFO
    if (c == 0)      { WAITVM(12); }
    else if (c == 7) { WAITVM(16); }
    else             { WAITVM(20); }
    if (c <= 5) stageA(c + 2, (c + 2) % 3);
    if (c <= 6) {
      #pragma unroll
      for (int n = 0; n < 4; ++n)
        bf[(2 * c + 2) & 3][n] = *(const bf16x8*)(bp + (2 * c + 2) * 2048 + n * 512);
      #pragma unroll
      for (int n = 0; n < 4; ++n)
        bf[(2 * c + 3) & 3][n] = *(const bf16x8*)(bp + (2 * c + 3) * 2048 + n * 512);
    }
    #pragma unroll
    for (int kk = 0; kk < 2; ++kk) {
      const int k = 2 * c + kk;
      const unsigned char* Ab = &ring[wave][c % 3][ul * 256];
      f32x4 a0 = *(const f32x4*)(Ab + ((kk * 128 + g * 32) ^ swz));
      f32x4 a1 = *(const f32x4*)(Ab + ((kk * 128 + g * 32 + 16) ^ swz));
      uint2 p0 = split2(a0[0], a0[1]);
      uint2 p1 = split2(a0[2], a0[3]);
      uint2 p2 = split2(a1[0], a1[1]);
      uint2 p3 = split2(a1[2], a1[3]);
      unsigned int hiw[4] = {p0.x, p1.x, p2.x, p3.x};
      unsigned int low[4] = {p0.y, p1.y, p2.y, p3.y};
      bf16x8 ahi, alo;
      memcpy(&ahi, hiw, 16);
      memcpy(&alo, low, 16);
      #pragma unroll
      for (int n = 0; n < 4; ++n) {
        acc[n] = __builtin_amdgcn_mfma_f32_16x16x32_bf16(ahi, bf[k & 3][n], acc[n], 0, 0, 0);
        acc[n] = __builtin_amdgcn_mfma_f32_16x16x32_bf16(alo, bf[k & 3][n], acc[n], 0, 0, 0);
      }
    }
  }

  // ---- wave-local scores + 16-row softmax (shuffles only) -----------------
  // C/D layout (m89/m91): row = g*4 + r, col u = n*16 + ul
  float psc[4];
  #pragma unroll
  for (int r = 0; r < 4; ++r) {
    float s = 0.f;
    #pragma unroll
    for (int n = 0; n < 4; ++n) {
      float z = acc[n][r] + dv[n];
      float ez = __expf(2.f * z);              // tanh via exp
      float th = 1.f - 2.f / (ez + 1.f);
      s = fmaf(th, vv[n], s);
    }
    s += __shfl_xor(s, 1);
    s += __shfl_xor(s, 2);
    s += __shfl_xor(s, 4);
    s += __shfl_xor(s, 8);     // all 16 lanes of the row group hold it
    psc[r] = s;
  }
  float m = fmaxf(fmaxf(psc[0], psc[1]), fmaxf(psc[2], psc[3]));
  m = fmaxf(m, __shfl_xor(m, 16));
  m = fmaxf(m, __shfl_xor(m, 32));   // tile max, all lanes
  float p[4];
  float lsum = 0.f;
  #pragma unroll
  for (int r = 0; r < 4; ++r) { p[r] = __expf(psc[r] - m); lsum += p[r]; }
  lsum += __shfl_xor(lsum, 16);
  lsum += __shfl_xor(lsum, 32);      // tile exp-sum, all lanes

  const int tl = q8 * 4 + wave;      // global tile id 0..31
  if (ul == 0) {
    float* att = out + (size_t)NB * ED + (size_t)b * SQ + row0w;
    #pragma unroll
    for (int r = 0; r < 4; ++r) att[g * 4 + r] = p[r];   // unnormalized
  }
  if (lane == 0) {
    mbuf[b * NT + tl] = m;
    lbuf[b * NT + tl] = lsum;
  }

  // ---- partial context (rows contiguous per instr, L2-hot) ----------------
  {
    const float* xrow = x + (size_t)(b * SQ + row0w) * ED + lane * 8;
    float4 pr0[4], pr1[4];
    #pragma unroll
    for (int q = 0; q < 4; ++q) {
      pr0[q] = *(const float4*)(xrow + (size_t)q * ED);
      pr1[q] = *(const float4*)(xrow + (size_t)q * ED + 4);
    }
    f32x4 c0 = zero4, c1 = zero4;
    #pragma unroll
    for (int i = 0; i < 16; ++i) {
      float4 v0 = pr0[i & 3], v1 = pr1[i & 3];
      if (i < 12) {
        pr0[i & 3] = *(const float4*)(xrow + (size_t)(i + 4) * ED);
        pr1[i & 3] = *(const float4*)(xrow + (size_t)(i + 4) * ED + 4);
      }
      float pi = __shfl(p[i & 3], (i >> 2) << 4);
      c0[0] = fmaf(pi, v0.x, c0[0]);
      c0[1] = fmaf(pi, v0.y, c0[1]);
      c0[2] = fmaf(pi, v0.z, c0[2]);
      c0[3] = fmaf(pi, v0.w, c0[3]);
      c1[0] = fmaf(pi, v1.x, c1[0]);
      c1[1] = fmaf(pi, v1.y, c1[1]);
      c1[2] = fmaf(pi, v1.z, c1[2]);
      c1[3] = fmaf(pi, v1.w, c1[3]);
    }
    float* ct = ctile + ((size_t)b * NT + tl) * ED + lane * 8;
    *(f32x4*)ct = c0;
    *(f32x4*)(ct + 4) = c1;
  }
}

// ---------------------------------------------------------------------------
// Kernel B: combine 32 tiles per batch (flash algebra).
// att *= e^{m_t-M}/L in place; ctx = sum_t ctile_t e^{m_t-M}/L.
// ---------------------------------------------------------------------------
__global__ __launch_bounds__(256) void combine(
    const float* __restrict__ mbuf, const float* __restrict__ lbuf,
    const float* __restrict__ ctile, float* __restrict__ out) {
  const int b = blockIdx.x;
  const int t = threadIdx.x;
  __shared__ float sc_s[NT];

  float M = -1e30f;
  #pragma unroll 8
  for (int j = 0; j < NT; ++j) M = fmaxf(M, mbuf[b * NT + j]);
  float L = 0.f;
  #pragma unroll 8
  for (int j = 0; j < NT; ++j) L += lbuf[b * NT + j] * __expf(mbuf[b * NT + j] - M);
  const float inv = 1.f / L;
  if (t < NT) sc_s[t] = __expf(mbuf[b * NT + t] - M) * inv;
  __syncthreads();

  float* att = out + (size_t)NB * ED + (size_t)b * SQ;
  #pragma unroll
  for (int s = t; s < SQ; s += 256) att[s] *= sc_s[s >> 4];

  const float* ct = ctile + (size_t)b * NT * ED;
  #pragma unroll
  for (int e = t; e < ED; e += 256) {
    float c = 0.f;
    #pragma unroll 8
    for (int j = 0; j < NT; ++j) c = fmaf(ct[j * ED + e], sc_s[j], c);
    out[(size_t)b * ED + e] = c;
  }
}

// ---------------------------------------------------------------------------
extern "C" void kernel_launch(void* const* d_in, const int* in_sizes, int n_in,
                              void* d_out, int out_size, void* d_ws, size_t ws_size,
                              hipStream_t stream) {
  const float* dh  = (const float*)d_in[0];
  const float* x   = (const float*)d_in[1];
  const float* w1  = (const float*)d_in[2];
  const float* w1b = (const float*)d_in[3];
  const float* w2  = (const float*)d_in[4];
  const float* w2b = (const float*)d_in[5];
  const float* vk  = (const float*)d_in[6];
  // d_in[7] = v_bias: softmax exactly invariant -> unused.
  unsigned short* wsb = (unsigned short*)d_ws;
  float* dec_ws = (float*)((char*)d_ws + WS_DEC);
  float* mbuf   = (float*)((char*)d_ws + WS_MBUF);
  float* lbuf   = (float*)((char*)d_ws + WS_LBUF);
  float* ctile  = (float*)((char*)d_ws + WS_CTILE);
  float* out = (float*)d_out;

  prep_all<<<384, 256, 0, stream>>>(w2, wsb, dh, w1, w1b, w2b, dec_ws);
  attn_blk<<<NB * 8, 256, 0, stream>>>(x, vk, wsb, dec_ws, mbuf, lbuf, ctile, out);
  combine<<<NB, 256, 0, stream>>>(mbuf, lbuf, ctile, out);
}